// Round 8
// baseline (235.730 us; speedup 1.0000x reference)
//
#include <hip/hip_runtime.h>
#include <hip/hip_bf16.h>
#include <hip/hip_fp16.h>

#define HEADS 4
#define C 32
#define OUTCH 128   // HEADS*C
#define INCH 128
#define NEG_SLOPE 0.2f

#define BKT 64        // dst nodes per bucket
#define BKT_BITS 6
#define SBL 256       // scatter blocks

struct alignas(8) h2x2 { __half2 a, b; };

// ---------------------------------------------------------------------------
// per-(bucket,block) histogram — no global atomics
// ---------------------------------------------------------------------------
__global__ __launch_bounds__(256) void k_hist(const int* __restrict__ dst,
                                              int* __restrict__ hist,
                                              int E, int NB, int chunk) {
    __shared__ int lh[1024];
    int blk = blockIdx.x;
    for (int i = threadIdx.x; i < NB; i += 256) lh[i] = 0;
    __syncthreads();
    int beg = blk * chunk, end = min(E, beg + chunk);
    for (int e = beg + threadIdx.x; e < end; e += 256)
        atomicAdd(&lh[dst[e] >> BKT_BITS], 1);
    __syncthreads();
    // XCD-major column so adjacent segments come from same-XCD blocks
    int cm = (blk & 7) * (SBL / 8) + (blk >> 3);
    for (int b = threadIdx.x; b < NB; b += 256) hist[b * SBL + cm] = lh[b];
}

// ---------------------------------------------------------------------------
// scan over NB*SBL entries (3 kernels)
// ---------------------------------------------------------------------------
__global__ __launch_bounds__(1024) void k_scan1(const int* __restrict__ v,
                                                int* __restrict__ incl,
                                                int* __restrict__ bsum, int n) {
    __shared__ int sm[1024];
    int t = threadIdx.x;
    int g = blockIdx.x * 1024 + t;
    int x = (g < n) ? v[g] : 0;
    sm[t] = x;
    __syncthreads();
    for (int off = 1; off < 1024; off <<= 1) {
        int add = (t >= off) ? sm[t - off] : 0;
        __syncthreads();
        sm[t] += add;
        __syncthreads();
    }
    if (g < n) incl[g] = sm[t];
    if (t == 1023) bsum[blockIdx.x] = sm[t];
}

__global__ __launch_bounds__(1024) void k_scan2(int* __restrict__ bsum, int nb) {
    __shared__ int sm[1024];
    int t = threadIdx.x;
    int x = (t < nb) ? bsum[t] : 0;
    sm[t] = x;
    __syncthreads();
    for (int off = 1; off < 1024; off <<= 1) {
        int add = (t >= off) ? sm[t - off] : 0;
        __syncthreads();
        sm[t] += add;
        __syncthreads();
    }
    if (t < nb) bsum[t] = sm[t] - x;  // exclusive
}

// exclusive result + sentinel at [n]
__global__ __launch_bounds__(1024) void k_scan3(const int* __restrict__ incl,
                                                const int* __restrict__ bsumx,
                                                const int* __restrict__ v,
                                                int* __restrict__ sOff, int n) {
    int g = blockIdx.x * 1024 + threadIdx.x;
    if (g < n) {
        int inc = incl[g] + bsumx[blockIdx.x];
        sOff[g] = inc - v[g];
        if (g == n - 1) sOff[n] = inc;
    }
}

// ---------------------------------------------------------------------------
// deterministic scatter: LDS cursors, fire-and-forget stores
// ---------------------------------------------------------------------------
__global__ __launch_bounds__(256) void k_scatter(const int* __restrict__ src,
                                                 const int* __restrict__ dst,
                                                 const int* __restrict__ sOff,
                                                 unsigned int* __restrict__ pairs,
                                                 int E, int NB, int chunk) {
    __shared__ int cur[1024];
    int blk = blockIdx.x;
    int cm = (blk & 7) * (SBL / 8) + (blk >> 3);
    for (int b = threadIdx.x; b < NB; b += 256) cur[b] = sOff[b * SBL + cm];
    __syncthreads();
    int beg = blk * chunk, end = min(E, beg + chunk);
    for (int e = beg + threadIdx.x; e < end; e += 256) {
        int d = dst[e];
        int b = d >> BKT_BITS;
        int pos = atomicAdd(&cur[b], 1);
        pairs[pos] = ((unsigned)(d & (BKT - 1)) << 26) | (unsigned)src[e];
    }
}

// ---------------------------------------------------------------------------
// bucket-local fine sort -> node-sorted CSR (srcl) + per-node offs/deg
// + dense per-edge exp precompute: ex[pos] = fp16x4 of exp(leaky(logit)).
// ---------------------------------------------------------------------------
__global__ __launch_bounds__(256) void k_bfillex(const unsigned int* __restrict__ pairs,
                                                 const int* __restrict__ sOff,
                                                 const float* __restrict__ a_src,
                                                 const float* __restrict__ a_dst,
                                                 int* __restrict__ offs,
                                                 int* __restrict__ deg,
                                                 int* __restrict__ srcl,
                                                 h2x2* __restrict__ ex, int n) {
    __shared__ int hist64[64];
    __shared__ int cur[64];
    __shared__ float ad[64][4];
    int b = blockIdx.x;
    int t = threadIdx.x;
    int n0 = b << BKT_BITS;
    int start = sOff[b * SBL];
    int end   = sOff[(b + 1) * SBL];
    if (t < 64) hist64[t] = 0;
    if (t < 256) {
        int node = n0 + (t >> 2);
        ad[t >> 2][t & 3] = (node < n) ? a_dst[(size_t)node * 4 + (t & 3)] : 0.f;
    }
    __syncthreads();
    for (int i = start + t; i < end; i += 256)
        atomicAdd(&hist64[pairs[i] >> 26], 1);
    __syncthreads();
    if (t < 64) {
        int v = hist64[t];
        int incl = v;
        for (int off = 1; off < 64; off <<= 1) {
            int u = __shfl_up(incl, off);
            if (t >= off) incl += u;
        }
        int excl = incl - v;
        cur[t] = start + excl;
        int node = n0 + t;
        if (node < n) { offs[node] = start + excl; deg[node] = v; }
    }
    __syncthreads();
    for (int i = start + t; i < end; i += 256) {
        unsigned p = pairs[i];
        int local = p >> 26;
        int s = p & 0x3FFFFFF;
        int pos = atomicAdd(&cur[local], 1);
        srcl[pos] = s;
        float4 as = *(const float4*)(a_src + (size_t)s * 4);
        float b0 = as.x + ad[local][0];
        float b1 = as.y + ad[local][1];
        float b2 = as.z + ad[local][2];
        float b3 = as.w + ad[local][3];
        b0 = fmaxf(b0, NEG_SLOPE * b0);
        b1 = fmaxf(b1, NEG_SLOPE * b1);
        b2 = fmaxf(b2, NEG_SLOPE * b2);
        b3 = fmaxf(b3, NEG_SLOPE * b3);
        h2x2 pk;
        pk.a = __floats2half2_rn(__expf(b0), __expf(b1));
        pk.b = __floats2half2_rn(__expf(b2), __expf(b3));
        ex[pos] = pk;
    }
}

// ---------------------------------------------------------------------------
// h16 = fp16(x @ W), fused attention logits (f32 accumulators, shuffle-reduce)
// ---------------------------------------------------------------------------
__global__ __launch_bounds__(256) void k_gemm(const float* __restrict__ x,
                                              const float* __restrict__ W,
                                              const float* __restrict__ att_src,
                                              const float* __restrict__ att_dst,
                                              __half* __restrict__ h16,
                                              float* __restrict__ a_src,
                                              float* __restrict__ a_dst, int n) {
    __shared__ float xs[64][128];
    int t = threadIdx.x;
    int rowBase = blockIdx.x * 64;
    for (int i = t; i < 64 * 32; i += 256) {
        int r = i >> 5, c4 = i & 31;
        float4 v = {0.f, 0.f, 0.f, 0.f};
        if (rowBase + r < n)
            v = *(const float4*)(x + (size_t)(rowBase + r) * INCH + c4 * 4);
        *(float4*)&xs[r][c4 * 4] = v;
    }
    __syncthreads();

    int colg = t & 31;
    int rowg = t >> 5;
    float acc[8][4] = {};
    const float4* W4 = (const float4*)W;
    for (int k = 0; k < 128; ++k) {
        float4 w = W4[k * 32 + colg];
#pragma unroll
        for (int i = 0; i < 8; ++i) {
            float xv = xs[rowg * 8 + i][k];
            acc[i][0] = fmaf(xv, w.x, acc[i][0]);
            acc[i][1] = fmaf(xv, w.y, acc[i][1]);
            acc[i][2] = fmaf(xv, w.z, acc[i][2]);
            acc[i][3] = fmaf(xv, w.w, acc[i][3]);
        }
    }

    int head = colg >> 3;
    float as4[4], ad4[4];
#pragma unroll
    for (int c = 0; c < 4; ++c) {
        int within = (colg & 7) * 4 + c;
        as4[c] = att_src[head * C + within];
        ad4[c] = att_dst[head * C + within];
    }
#pragma unroll
    for (int i = 0; i < 8; ++i) {
        int r = rowBase + rowg * 8 + i;
        if (r < n) {
            h2x2 pk;
            pk.a = __floats2half2_rn(acc[i][0], acc[i][1]);
            pk.b = __floats2half2_rn(acc[i][2], acc[i][3]);
            *(h2x2*)(h16 + (size_t)r * OUTCH + colg * 4) = pk;
        }
        float ps = acc[i][0] * as4[0] + acc[i][1] * as4[1] +
                   acc[i][2] * as4[2] + acc[i][3] * as4[3];
        float pd = acc[i][0] * ad4[0] + acc[i][1] * ad4[1] +
                   acc[i][2] * ad4[2] + acc[i][3] * ad4[3];
        ps += __shfl_xor(ps, 1); ps += __shfl_xor(ps, 2); ps += __shfl_xor(ps, 4);
        pd += __shfl_xor(pd, 1); pd += __shfl_xor(pd, 2); pd += __shfl_xor(pd, 4);
        if ((colg & 7) == 0 && r < n) {
            a_src[(size_t)r * 4 + head] = ps;
            a_dst[(size_t)r * 4 + head] = pd;
        }
    }
}

// ---------------------------------------------------------------------------
// aggregation: one wave per node; full wave per edge (64 lanes x half2 = 256B
// coalesced row); exp precomputed (ex stream); 4-way unroll.
// ---------------------------------------------------------------------------
__global__ __launch_bounds__(256) void k_aggr(const __half* __restrict__ h16,
                                              const __half* __restrict__ ex,
                                              const float* __restrict__ a_src,
                                              const float* __restrict__ a_dst,
                                              const int* __restrict__ offs,
                                              const int* __restrict__ deg,
                                              const int* __restrict__ srcl,
                                              const float* __restrict__ bias,
                                              float* __restrict__ out, int n) {
    int w = (blockIdx.x * 256 + threadIdx.x) >> 6;
    if (w >= n) return;
    int lane = threadIdx.x & 63;
    int head = lane >> 4;   // 16 lanes (32 ch) per head
    int ch = lane << 1;
    const __half2* H2 = (const __half2*)h16;  // row stride 64

    // self-loop
    float al = a_src[(size_t)w * 4 + head] + a_dst[(size_t)w * 4 + head];
    al = fmaxf(al, NEG_SLOPE * al);
    float exs = __expf(al);
    float2 hv = __half22float2(H2[(size_t)w * 64 + lane]);
    float f0 = exs * hv.x, f1 = exs * hv.y, den = exs;

    int start = offs[w], d = deg[w];
    int j = 0;
    for (; j + 4 <= d; j += 4) {
        size_t p = (size_t)(start + j);
        int s0 = srcl[p];
        int s1 = srcl[p + 1];
        int s2 = srcl[p + 2];
        int s3 = srcl[p + 3];
        float e0 = __half2float(ex[p * 4 + head]);
        float e1 = __half2float(ex[(p + 1) * 4 + head]);
        float e2 = __half2float(ex[(p + 2) * 4 + head]);
        float e3 = __half2float(ex[(p + 3) * 4 + head]);
        __half2 g0 = H2[(size_t)s0 * 64 + lane];
        __half2 g1 = H2[(size_t)s1 * 64 + lane];
        __half2 g2 = H2[(size_t)s2 * 64 + lane];
        __half2 g3 = H2[(size_t)s3 * 64 + lane];
        den += (e0 + e1) + (e2 + e3);
        float2 G0 = __half22float2(g0);
        float2 G1 = __half22float2(g1);
        float2 G2 = __half22float2(g2);
        float2 G3 = __half22float2(g3);
        f0 = fmaf(e0, G0.x, f0); f1 = fmaf(e0, G0.y, f1);
        f0 = fmaf(e1, G1.x, f0); f1 = fmaf(e1, G1.y, f1);
        f0 = fmaf(e2, G2.x, f0); f1 = fmaf(e2, G2.y, f1);
        f0 = fmaf(e3, G3.x, f0); f1 = fmaf(e3, G3.y, f1);
    }
    for (; j < d; ++j) {
        size_t p = (size_t)(start + j);
        int s0 = srcl[p];
        float e0 = __half2float(ex[p * 4 + head]);
        __half2 g0 = H2[(size_t)s0 * 64 + lane];
        den += e0;
        float2 G0 = __half22float2(g0);
        f0 = fmaf(e0, G0.x, f0); f1 = fmaf(e0, G0.y, f1);
    }

    float inv = 1.0f / den;
    float2 bv = *(const float2*)(bias + ch);
    float2 o;
    o.x = f0 * inv + bv.x;
    o.y = f1 * inv + bv.y;
    *(float2*)(out + (size_t)w * OUTCH + ch) = o;
}

// ---------------------------------------------------------------------------
extern "C" void kernel_launch(void* const* d_in, const int* in_sizes, int n_in,
                              void* d_out, int out_size, void* d_ws, size_t ws_size,
                              hipStream_t stream) {
    const float* x       = (const float*)d_in[0];
    const int*   edge    = (const int*)d_in[1];
    const float* W       = (const float*)d_in[2];
    const float* att_src = (const float*)d_in[3];
    const float* att_dst = (const float*)d_in[4];
    const float* bias    = (const float*)d_in[5];
    float* out = (float*)d_out;

    const int N = in_sizes[0] / INCH;
    const int E = in_sizes[1] / 2;
    const int* esrc = edge;
    const int* edst = edge + E;

    const int NB = (N + BKT - 1) >> BKT_BITS;   // buckets (<=1024)
    const int n2 = NB * SBL;                    // scan length
    const int chunk = (E + SBL - 1) / SBL;

    auto align = [](size_t v) { return (v + 255) & ~(size_t)255; };
    char* p = (char*)d_ws;
    __half* h16   = (__half*)p; p += align((size_t)N * OUTCH * 2);
    float* a_src  = (float*)p; p += align((size_t)N * 4 * 4);
    float* a_dst  = (float*)p; p += align((size_t)N * 4 * 4);
    int*   hist   = (int*)p;   p += align((size_t)n2 * 4);
    int*   incl   = (int*)p;   p += align((size_t)(n2 + 1) * 4);
    int*   sOff   = (int*)p;   p += align((size_t)(n2 + 1) * 4);
    int*   bsum   = (int*)p;   p += align(1024 * 4);
    int*   offs   = (int*)p;   p += align((size_t)N * 4);
    int*   deg    = (int*)p;   p += align((size_t)N * 4);
    unsigned int* pairs = (unsigned int*)p; p += align((size_t)E * 4);
    int*   srcl   = (int*)p;   p += align((size_t)E * 4);
    h2x2*  ex     = (h2x2*)p;  p += align((size_t)E * 8);

    const int SCB = (n2 + 1023) / 1024;

    k_gemm<<<(N + 63) / 64, 256, 0, stream>>>(x, W, att_src, att_dst, h16, a_src, a_dst, N);

    k_hist<<<SBL, 256, 0, stream>>>(edst, hist, E, NB, chunk);
    k_scan1<<<SCB, 1024, 0, stream>>>(hist, incl, bsum, n2);
    k_scan2<<<1, 1024, 0, stream>>>(bsum, SCB);
    k_scan3<<<SCB, 1024, 0, stream>>>(incl, bsum, hist, sOff, n2);
    k_scatter<<<SBL, 256, 0, stream>>>(esrc, edst, sOff, pairs, E, NB, chunk);
    k_bfillex<<<NB, 256, 0, stream>>>(pairs, sOff, a_src, a_dst, offs, deg, srcl, ex, N);

    k_aggr<<<(N + 3) / 4, 256, 0, stream>>>(h16, (const __half*)ex, a_src, a_dst,
                                            offs, deg, srcl, bias, out, N);
}

// Round 9
// 228.007 us; speedup vs baseline: 1.0339x; 1.0339x over previous
//
#include <hip/hip_runtime.h>
#include <hip/hip_bf16.h>
#include <hip/hip_fp16.h>

#define HEADS 4
#define C 32
#define OUTCH 128   // HEADS*C
#define INCH 128
#define NEG_SLOPE 0.2f

#define BKT 64        // dst nodes per bucket
#define BKT_BITS 6
#define SBL 256       // scatter blocks

struct alignas(8) h2x2 { __half2 a, b; };

// ---------------------------------------------------------------------------
// per-(bucket,block) histogram — no global atomics
// ---------------------------------------------------------------------------
__global__ __launch_bounds__(256) void k_hist(const int* __restrict__ dst,
                                              int* __restrict__ hist,
                                              int E, int NB, int chunk) {
    __shared__ int lh[1024];
    int blk = blockIdx.x;
    for (int i = threadIdx.x; i < NB; i += 256) lh[i] = 0;
    __syncthreads();
    int beg = blk * chunk, end = min(E, beg + chunk);
    for (int e = beg + threadIdx.x; e < end; e += 256)
        atomicAdd(&lh[dst[e] >> BKT_BITS], 1);
    __syncthreads();
    // XCD-major column so adjacent segments come from same-XCD blocks
    int cm = (blk & 7) * (SBL / 8) + (blk >> 3);
    for (int b = threadIdx.x; b < NB; b += 256) hist[b * SBL + cm] = lh[b];
}

// ---------------------------------------------------------------------------
// scan over NB*SBL entries (3 kernels)
// ---------------------------------------------------------------------------
__global__ __launch_bounds__(1024) void k_scan1(const int* __restrict__ v,
                                                int* __restrict__ incl,
                                                int* __restrict__ bsum, int n) {
    __shared__ int sm[1024];
    int t = threadIdx.x;
    int g = blockIdx.x * 1024 + t;
    int x = (g < n) ? v[g] : 0;
    sm[t] = x;
    __syncthreads();
    for (int off = 1; off < 1024; off <<= 1) {
        int add = (t >= off) ? sm[t - off] : 0;
        __syncthreads();
        sm[t] += add;
        __syncthreads();
    }
    if (g < n) incl[g] = sm[t];
    if (t == 1023) bsum[blockIdx.x] = sm[t];
}

__global__ __launch_bounds__(1024) void k_scan2(int* __restrict__ bsum, int nb) {
    __shared__ int sm[1024];
    int t = threadIdx.x;
    int x = (t < nb) ? bsum[t] : 0;
    sm[t] = x;
    __syncthreads();
    for (int off = 1; off < 1024; off <<= 1) {
        int add = (t >= off) ? sm[t - off] : 0;
        __syncthreads();
        sm[t] += add;
        __syncthreads();
    }
    if (t < nb) bsum[t] = sm[t] - x;  // exclusive
}

// exclusive result + sentinel at [n]
__global__ __launch_bounds__(1024) void k_scan3(const int* __restrict__ incl,
                                                const int* __restrict__ bsumx,
                                                const int* __restrict__ v,
                                                int* __restrict__ sOff, int n) {
    int g = blockIdx.x * 1024 + threadIdx.x;
    if (g < n) {
        int inc = incl[g] + bsumx[blockIdx.x];
        sOff[g] = inc - v[g];
        if (g == n - 1) sOff[n] = inc;
    }
}

// ---------------------------------------------------------------------------
// deterministic scatter: LDS cursors, fire-and-forget stores
// ---------------------------------------------------------------------------
__global__ __launch_bounds__(256) void k_scatter(const int* __restrict__ src,
                                                 const int* __restrict__ dst,
                                                 const int* __restrict__ sOff,
                                                 unsigned int* __restrict__ pairs,
                                                 int E, int NB, int chunk) {
    __shared__ int cur[1024];
    int blk = blockIdx.x;
    int cm = (blk & 7) * (SBL / 8) + (blk >> 3);
    for (int b = threadIdx.x; b < NB; b += 256) cur[b] = sOff[b * SBL + cm];
    __syncthreads();
    int beg = blk * chunk, end = min(E, beg + chunk);
    for (int e = beg + threadIdx.x; e < end; e += 256) {
        int d = dst[e];
        int b = d >> BKT_BITS;
        int pos = atomicAdd(&cur[b], 1);
        pairs[pos] = ((unsigned)(d & (BKT - 1)) << 26) | (unsigned)src[e];
    }
}

// ---------------------------------------------------------------------------
// bucket-local fine sort -> node-sorted CSR (srcl) + per-node offs/deg
// + dense per-edge exp precompute: ex[pos] = fp16x4 of exp(leaky(logit)).
// ---------------------------------------------------------------------------
__global__ __launch_bounds__(256) void k_bfillex(const unsigned int* __restrict__ pairs,
                                                 const int* __restrict__ sOff,
                                                 const float* __restrict__ a_src,
                                                 const float* __restrict__ a_dst,
                                                 int* __restrict__ offs,
                                                 int* __restrict__ deg,
                                                 int* __restrict__ srcl,
                                                 h2x2* __restrict__ ex, int n) {
    __shared__ int hist64[64];
    __shared__ int cur[64];
    __shared__ float ad[64][4];
    int b = blockIdx.x;
    int t = threadIdx.x;
    int n0 = b << BKT_BITS;
    int start = sOff[b * SBL];
    int end   = sOff[(b + 1) * SBL];
    if (t < 64) hist64[t] = 0;
    if (t < 256) {
        int node = n0 + (t >> 2);
        ad[t >> 2][t & 3] = (node < n) ? a_dst[(size_t)node * 4 + (t & 3)] : 0.f;
    }
    __syncthreads();
    for (int i = start + t; i < end; i += 256)
        atomicAdd(&hist64[pairs[i] >> 26], 1);
    __syncthreads();
    if (t < 64) {
        int v = hist64[t];
        int incl = v;
        for (int off = 1; off < 64; off <<= 1) {
            int u = __shfl_up(incl, off);
            if (t >= off) incl += u;
        }
        int excl = incl - v;
        cur[t] = start + excl;
        int node = n0 + t;
        if (node < n) { offs[node] = start + excl; deg[node] = v; }
    }
    __syncthreads();
    for (int i = start + t; i < end; i += 256) {
        unsigned p = pairs[i];
        int local = p >> 26;
        int s = p & 0x3FFFFFF;
        int pos = atomicAdd(&cur[local], 1);
        srcl[pos] = s;
        float4 as = *(const float4*)(a_src + (size_t)s * 4);
        float b0 = as.x + ad[local][0];
        float b1 = as.y + ad[local][1];
        float b2 = as.z + ad[local][2];
        float b3 = as.w + ad[local][3];
        b0 = fmaxf(b0, NEG_SLOPE * b0);
        b1 = fmaxf(b1, NEG_SLOPE * b1);
        b2 = fmaxf(b2, NEG_SLOPE * b2);
        b3 = fmaxf(b3, NEG_SLOPE * b3);
        h2x2 pk;
        pk.a = __floats2half2_rn(__expf(b0), __expf(b1));
        pk.b = __floats2half2_rn(__expf(b2), __expf(b3));
        ex[pos] = pk;
    }
}

// ---------------------------------------------------------------------------
// h16 = fp16(x @ W), fused attention logits (f32 accumulators, shuffle-reduce)
// ---------------------------------------------------------------------------
__global__ __launch_bounds__(256) void k_gemm(const float* __restrict__ x,
                                              const float* __restrict__ W,
                                              const float* __restrict__ att_src,
                                              const float* __restrict__ att_dst,
                                              __half* __restrict__ h16,
                                              float* __restrict__ a_src,
                                              float* __restrict__ a_dst, int n) {
    __shared__ float xs[64][128];
    int t = threadIdx.x;
    int rowBase = blockIdx.x * 64;
    for (int i = t; i < 64 * 32; i += 256) {
        int r = i >> 5, c4 = i & 31;
        float4 v = {0.f, 0.f, 0.f, 0.f};
        if (rowBase + r < n)
            v = *(const float4*)(x + (size_t)(rowBase + r) * INCH + c4 * 4);
        *(float4*)&xs[r][c4 * 4] = v;
    }
    __syncthreads();

    int colg = t & 31;
    int rowg = t >> 5;
    float acc[8][4] = {};
    const float4* W4 = (const float4*)W;
    for (int k = 0; k < 128; ++k) {
        float4 w = W4[k * 32 + colg];
#pragma unroll
        for (int i = 0; i < 8; ++i) {
            float xv = xs[rowg * 8 + i][k];
            acc[i][0] = fmaf(xv, w.x, acc[i][0]);
            acc[i][1] = fmaf(xv, w.y, acc[i][1]);
            acc[i][2] = fmaf(xv, w.z, acc[i][2]);
            acc[i][3] = fmaf(xv, w.w, acc[i][3]);
        }
    }

    int head = colg >> 3;
    float as4[4], ad4[4];
#pragma unroll
    for (int c = 0; c < 4; ++c) {
        int within = (colg & 7) * 4 + c;
        as4[c] = att_src[head * C + within];
        ad4[c] = att_dst[head * C + within];
    }
#pragma unroll
    for (int i = 0; i < 8; ++i) {
        int r = rowBase + rowg * 8 + i;
        if (r < n) {
            h2x2 pk;
            pk.a = __floats2half2_rn(acc[i][0], acc[i][1]);
            pk.b = __floats2half2_rn(acc[i][2], acc[i][3]);
            *(h2x2*)(h16 + (size_t)r * OUTCH + colg * 4) = pk;
        }
        float ps = acc[i][0] * as4[0] + acc[i][1] * as4[1] +
                   acc[i][2] * as4[2] + acc[i][3] * as4[3];
        float pd = acc[i][0] * ad4[0] + acc[i][1] * ad4[1] +
                   acc[i][2] * ad4[2] + acc[i][3] * ad4[3];
        ps += __shfl_xor(ps, 1); ps += __shfl_xor(ps, 2); ps += __shfl_xor(ps, 4);
        pd += __shfl_xor(pd, 1); pd += __shfl_xor(pd, 2); pd += __shfl_xor(pd, 4);
        if ((colg & 7) == 0 && r < n) {
            a_src[(size_t)r * 4 + head] = ps;
            a_dst[(size_t)r * 4 + head] = pd;
        }
    }
}

// ---------------------------------------------------------------------------
// aggregation: one wave per node; full wave per edge (64 lanes x half2 = 256B
// coalesced row); exp precomputed (ex stream); 8-way unroll for MLP.
// ---------------------------------------------------------------------------
__global__ __launch_bounds__(256) void k_aggr(const __half* __restrict__ h16,
                                              const __half* __restrict__ ex,
                                              const float* __restrict__ a_src,
                                              const float* __restrict__ a_dst,
                                              const int* __restrict__ offs,
                                              const int* __restrict__ deg,
                                              const int* __restrict__ srcl,
                                              const float* __restrict__ bias,
                                              float* __restrict__ out, int n) {
    int w = (blockIdx.x * 256 + threadIdx.x) >> 6;
    if (w >= n) return;
    int lane = threadIdx.x & 63;
    int head = lane >> 4;   // 16 lanes (32 ch) per head
    int ch = lane << 1;
    const __half2* H2 = (const __half2*)h16;  // row stride 64

    // self-loop
    float al = a_src[(size_t)w * 4 + head] + a_dst[(size_t)w * 4 + head];
    al = fmaxf(al, NEG_SLOPE * al);
    float exs = __expf(al);
    float2 hv = __half22float2(H2[(size_t)w * 64 + lane]);
    float f0 = exs * hv.x, f1 = exs * hv.y, den = exs;

    int start = offs[w], d = deg[w];
    int j = 0;
    for (; j + 8 <= d; j += 8) {
        size_t p = (size_t)(start + j);
        int s0 = srcl[p];
        int s1 = srcl[p + 1];
        int s2 = srcl[p + 2];
        int s3 = srcl[p + 3];
        int s4 = srcl[p + 4];
        int s5 = srcl[p + 5];
        int s6 = srcl[p + 6];
        int s7 = srcl[p + 7];
        __half2 g0 = H2[(size_t)s0 * 64 + lane];
        __half2 g1 = H2[(size_t)s1 * 64 + lane];
        __half2 g2 = H2[(size_t)s2 * 64 + lane];
        __half2 g3 = H2[(size_t)s3 * 64 + lane];
        __half2 g4 = H2[(size_t)s4 * 64 + lane];
        __half2 g5 = H2[(size_t)s5 * 64 + lane];
        __half2 g6 = H2[(size_t)s6 * 64 + lane];
        __half2 g7 = H2[(size_t)s7 * 64 + lane];
        float e0 = __half2float(ex[p * 4 + head]);
        float e1 = __half2float(ex[(p + 1) * 4 + head]);
        float e2 = __half2float(ex[(p + 2) * 4 + head]);
        float e3 = __half2float(ex[(p + 3) * 4 + head]);
        float e4 = __half2float(ex[(p + 4) * 4 + head]);
        float e5 = __half2float(ex[(p + 5) * 4 + head]);
        float e6 = __half2float(ex[(p + 6) * 4 + head]);
        float e7 = __half2float(ex[(p + 7) * 4 + head]);
        den += ((e0 + e1) + (e2 + e3)) + ((e4 + e5) + (e6 + e7));
        float2 G;
        G = __half22float2(g0); f0 = fmaf(e0, G.x, f0); f1 = fmaf(e0, G.y, f1);
        G = __half22float2(g1); f0 = fmaf(e1, G.x, f0); f1 = fmaf(e1, G.y, f1);
        G = __half22float2(g2); f0 = fmaf(e2, G.x, f0); f1 = fmaf(e2, G.y, f1);
        G = __half22float2(g3); f0 = fmaf(e3, G.x, f0); f1 = fmaf(e3, G.y, f1);
        G = __half22float2(g4); f0 = fmaf(e4, G.x, f0); f1 = fmaf(e4, G.y, f1);
        G = __half22float2(g5); f0 = fmaf(e5, G.x, f0); f1 = fmaf(e5, G.y, f1);
        G = __half22float2(g6); f0 = fmaf(e6, G.x, f0); f1 = fmaf(e6, G.y, f1);
        G = __half22float2(g7); f0 = fmaf(e7, G.x, f0); f1 = fmaf(e7, G.y, f1);
    }
    for (; j + 4 <= d; j += 4) {
        size_t p = (size_t)(start + j);
        int s0 = srcl[p];
        int s1 = srcl[p + 1];
        int s2 = srcl[p + 2];
        int s3 = srcl[p + 3];
        __half2 g0 = H2[(size_t)s0 * 64 + lane];
        __half2 g1 = H2[(size_t)s1 * 64 + lane];
        __half2 g2 = H2[(size_t)s2 * 64 + lane];
        __half2 g3 = H2[(size_t)s3 * 64 + lane];
        float e0 = __half2float(ex[p * 4 + head]);
        float e1 = __half2float(ex[(p + 1) * 4 + head]);
        float e2 = __half2float(ex[(p + 2) * 4 + head]);
        float e3 = __half2float(ex[(p + 3) * 4 + head]);
        den += (e0 + e1) + (e2 + e3);
        float2 G;
        G = __half22float2(g0); f0 = fmaf(e0, G.x, f0); f1 = fmaf(e0, G.y, f1);
        G = __half22float2(g1); f0 = fmaf(e1, G.x, f0); f1 = fmaf(e1, G.y, f1);
        G = __half22float2(g2); f0 = fmaf(e2, G.x, f0); f1 = fmaf(e2, G.y, f1);
        G = __half22float2(g3); f0 = fmaf(e3, G.x, f0); f1 = fmaf(e3, G.y, f1);
    }
    for (; j < d; ++j) {
        size_t p = (size_t)(start + j);
        int s0 = srcl[p];
        float e0 = __half2float(ex[p * 4 + head]);
        __half2 g0 = H2[(size_t)s0 * 64 + lane];
        den += e0;
        float2 G0 = __half22float2(g0);
        f0 = fmaf(e0, G0.x, f0); f1 = fmaf(e0, G0.y, f1);
    }

    float inv = 1.0f / den;
    float2 bv = *(const float2*)(bias + ch);
    float2 o;
    o.x = f0 * inv + bv.x;
    o.y = f1 * inv + bv.y;
    *(float2*)(out + (size_t)w * OUTCH + ch) = o;
}

// ---------------------------------------------------------------------------
extern "C" void kernel_launch(void* const* d_in, const int* in_sizes, int n_in,
                              void* d_out, int out_size, void* d_ws, size_t ws_size,
                              hipStream_t stream) {
    const float* x       = (const float*)d_in[0];
    const int*   edge    = (const int*)d_in[1];
    const float* W       = (const float*)d_in[2];
    const float* att_src = (const float*)d_in[3];
    const float* att_dst = (const float*)d_in[4];
    const float* bias    = (const float*)d_in[5];
    float* out = (float*)d_out;

    const int N = in_sizes[0] / INCH;
    const int E = in_sizes[1] / 2;
    const int* esrc = edge;
    const int* edst = edge + E;

    const int NB = (N + BKT - 1) >> BKT_BITS;   // buckets (<=1024)
    const int n2 = NB * SBL;                    // scan length
    const int chunk = (E + SBL - 1) / SBL;

    auto align = [](size_t v) { return (v + 255) & ~(size_t)255; };
    char* p = (char*)d_ws;
    __half* h16   = (__half*)p; p += align((size_t)N * OUTCH * 2);
    float* a_src  = (float*)p; p += align((size_t)N * 4 * 4);
    float* a_dst  = (float*)p; p += align((size_t)N * 4 * 4);
    int*   hist   = (int*)p;   p += align((size_t)n2 * 4);
    int*   incl   = (int*)p;   p += align((size_t)(n2 + 1) * 4);
    int*   sOff   = (int*)p;   p += align((size_t)(n2 + 1) * 4);
    int*   bsum   = (int*)p;   p += align(1024 * 4);
    int*   offs   = (int*)p;   p += align((size_t)N * 4);
    int*   deg    = (int*)p;   p += align((size_t)N * 4);
    unsigned int* pairs = (unsigned int*)p; p += align((size_t)E * 4);
    int*   srcl   = (int*)p;   p += align((size_t)E * 4);
    h2x2*  ex     = (h2x2*)p;  p += align((size_t)E * 8);

    const int SCB = (n2 + 1023) / 1024;

    k_gemm<<<(N + 63) / 64, 256, 0, stream>>>(x, W, att_src, att_dst, h16, a_src, a_dst, N);

    k_hist<<<SBL, 256, 0, stream>>>(edst, hist, E, NB, chunk);
    k_scan1<<<SCB, 1024, 0, stream>>>(hist, incl, bsum, n2);
    k_scan2<<<1, 1024, 0, stream>>>(bsum, SCB);
    k_scan3<<<SCB, 1024, 0, stream>>>(incl, bsum, hist, sOff, n2);
    k_scatter<<<SBL, 256, 0, stream>>>(esrc, edst, sOff, pairs, E, NB, chunk);
    k_bfillex<<<NB, 256, 0, stream>>>(pairs, sOff, a_src, a_dst, offs, deg, srcl, ex, N);

    k_aggr<<<(N + 3) / 4, 256, 0, stream>>>(h16, (const __half*)ex, a_src, a_dst,
                                            offs, deg, srcl, bias, out, N);
}